// Round 11
// baseline (324.135 us; speedup 1.0000x reference)
//
#include <hip/hip_runtime.h>

// h = x(65536x512) @ W^T(512x256) + bias_lin ; GroupNorm(8 groups of 32)
// ; min over 256 channels -> m[b] ; out[c*B+b] = m[b] + bias[c]
//
// R11: LDS-free, barrier-free streaming GEMM. All prior rounds shared one
// inner recipe (fp32 X -> VALU cvt -> LDS stage -> ds_read by every wave ->
// MFMA, multi-phase barriers); per-tile cost (~10us/CU) was invariant to
// every structure around it. This kernel deletes the recipe: wave owns 32
// channels (one GN group; bfr=128 VGPR), X fragments loaded DIRECTLY from
// global to registers (lane reads its own 32B; wave touches 16 rows x
// 128-B full lines; L1 serves the 2nd half-line), GroupNorm fully in-wave
// (8 in-lane + shfl_xor 16/32), per-wave 32-ch row-min -> mparts[8][B].
// ZERO LDS, ZERO __syncthreads. Block = 4 waves = 128 ch (part); 2 parts
// per tile, same XCD + temporally adjacent (xcd=bid&7) for L2 reuse.
// bcast_out: 8-way min + bias, coalesced.
#define B_ROWS 65536
#define K_DIM  512
#define N_DIM  256
#define EPS    1e-5f
#define MTILE  32
#define TILES  (B_ROWS / MTILE)       // 2048

using short8  = __attribute__((ext_vector_type(8))) short;
using floatx4 = __attribute__((ext_vector_type(4))) float;

__device__ __forceinline__ unsigned short f2bf(float f) {
    unsigned u = __builtin_bit_cast(unsigned, f);
    u += 0x7FFFu + ((u >> 16) & 1u);     // RNE
    return (unsigned short)(u >> 16);
}

// Pack W (256x512 fp32) into bf16 MFMA fragment order (A/B layouts symmetric
// for 16x16x32):
// P[((nt*16 + kkg)*64 + lane)*8 + j] = bf16(W[nt*16 + (lane&15)][kkg*32 + (lane>>4)*8 + j])
__global__ __launch_bounds__(64) void pack_w(const float* __restrict__ W,
                                             unsigned short* __restrict__ P) {
    int b    = blockIdx.x;           // 0..255
    int nt   = b >> 4, kk = b & 15;
    int lane = threadIdx.x;
    int l15  = lane & 15, quad = lane >> 4;
    const float* src = W + (size_t)(nt * 16 + l15) * K_DIM + kk * 32 + quad * 8;
    short8 v;
#pragma unroll
    for (int j = 0; j < 8; ++j) v[j] = (short)f2bf(src[j]);
    *(short8*)(P + ((size_t)(nt * 16 + kk) * 64 + lane) * 8) = v;
}

// grid 4096 x 256 thr. Block covers tile (32 rows) x 128 ch; wave owns 32 ch.
__global__ __launch_bounds__(256) void gemm_gn_stream(
    const float* __restrict__ X, const unsigned short* __restrict__ P,
    const float* __restrict__ bias_lin, const float* __restrict__ wgn,
    const float* __restrict__ bgn, float* __restrict__ mparts)
{
    const int tid  = threadIdx.x;
    const int wave = tid >> 6;            // 0..3
    const int lane = tid & 63;
    const int l15  = lane & 15, quad = lane >> 4;

    const int bid  = blockIdx.x;          // 0..4095
    const int xcd  = bid & 7;
    const int j    = bid >> 3;            // 0..511
    const int tile = xcd * 256 + (j >> 1);
    const int part = j & 1;

    const int cbase = part * 128 + wave * 32;   // wave's 32 channels (one GN group)
    const int nt0   = cbase >> 4;               // 2 nt blocks: nt0, nt0+1

    // ---- W fragments for the wave's 32 channels: 2 x 16 short8 = 128 VGPR ----
    short8 bfr[2][16];
#pragma unroll
    for (int ct = 0; ct < 2; ++ct)
#pragma unroll
        for (int kkg = 0; kkg < 16; ++kkg)
            bfr[ct][kkg] = *(const short8*)(P + (((size_t)(nt0 + ct) * 16 + kkg) * 64 + lane) * 8);

    // per-lane channel params: ch = cbase + ct*16 + quad*4 + r
    float blr[2][4], wgr[2][4], bgr[2][4];
#pragma unroll
    for (int ct = 0; ct < 2; ++ct)
#pragma unroll
        for (int r = 0; r < 4; ++r) {
            int c = cbase + ct * 16 + quad * 4 + r;
            blr[ct][r] = bias_lin[c]; wgr[ct][r] = wgn[c]; bgr[ct][r] = bgn[c];
        }

    // ---- K-loop: X fragments straight from global (no LDS) ----
    floatx4 acc[2][2];                    // [ct][rt]
#pragma unroll
    for (int ct = 0; ct < 2; ++ct)
#pragma unroll
        for (int rt = 0; rt < 2; ++rt)
#pragma unroll
            for (int r = 0; r < 4; ++r) acc[ct][rt][r] = blr[ct][r];

    // lane's X address: row = tile*32 + rt*16 + l15, cols kk*32 + quad*8 + [0,8)
    const float* xl = X + ((size_t)tile * MTILE + l15) * K_DIM + quad * 8;
#pragma unroll
    for (int kk = 0; kk < 16; ++kk) {
#pragma unroll
        for (int rt = 0; rt < 2; ++rt) {
            const float* p = xl + (size_t)rt * 16 * K_DIM + kk * 32;
            float4 lo = *(const float4*)p;
            float4 hi = *(const float4*)(p + 4);
            short8 xf;
            xf[0] = (short)f2bf(lo.x); xf[1] = (short)f2bf(lo.y);
            xf[2] = (short)f2bf(lo.z); xf[3] = (short)f2bf(lo.w);
            xf[4] = (short)f2bf(hi.x); xf[5] = (short)f2bf(hi.y);
            xf[6] = (short)f2bf(hi.z); xf[7] = (short)f2bf(hi.w);
            acc[0][rt] = __builtin_amdgcn_mfma_f32_16x16x32_bf16(bfr[0][kk], xf, acc[0][rt], 0, 0, 0);
            acc[1][rt] = __builtin_amdgcn_mfma_f32_16x16x32_bf16(bfr[1][kk], xf, acc[1][rt], 0, 0, 0);
        }
    }

    // ---- GroupNorm (32 ch, fully in-wave) + row-min -> mparts ----
#pragma unroll
    for (int rt = 0; rt < 2; ++rt) {
        float s = 0.f, ss = 0.f;
#pragma unroll
        for (int ct = 0; ct < 2; ++ct)
#pragma unroll
            for (int r = 0; r < 4; ++r) {
                float v = acc[ct][rt][r];
                s += v; ss = fmaf(v, v, ss);
            }
        s  += __shfl_xor(s, 16);  s  += __shfl_xor(s, 32);
        ss += __shfl_xor(ss, 16); ss += __shfl_xor(ss, 32);
        float mean = s * (1.0f / 32.0f);
        float var  = ss * (1.0f / 32.0f) - mean * mean;
        float inv  = rsqrtf(var + EPS);
        float mi   = mean * inv;
        float mn   = 1e30f;
#pragma unroll
        for (int ct = 0; ct < 2; ++ct)
#pragma unroll
            for (int r = 0; r < 4; ++r) {
                float g = fmaf(fmaf(acc[ct][rt][r], inv, -mi), wgr[ct][r], bgr[ct][r]);
                mn = fminf(mn, g);
            }
        mn = fminf(mn, __shfl_xor(mn, 16));
        mn = fminf(mn, __shfl_xor(mn, 32));
        if (quad == 0)
            mparts[(size_t)(part * 4 + wave) * B_ROWS + (size_t)tile * MTILE + rt * 16 + l15] = mn;
    }
}

// out[c*B + b] = min over 8 parts of mparts[g][b], + bias[c].
__global__ __launch_bounds__(256) void bcast_out(
    const float* __restrict__ mparts, const float* __restrict__ bias,
    float* __restrict__ out)
{
    float4*       o4 = (float4*)out;
    const int bid = blockIdx.x;          // 0..2047
    const int c   = bid >> 3;            // 8 blocks per channel
    const float bc = bias[c];
    const int base = (bid & 7) * 2048;   // float4 offset within channel
#pragma unroll
    for (int k = 0; k < 8; ++k) {
        int idx = base + k * 256 + threadIdx.x;          // 0..16383
        float4 mn = ((const float4*)mparts)[idx];
#pragma unroll
        for (int g = 1; g < 8; ++g) {
            float4 v = ((const float4*)(mparts + (size_t)g * B_ROWS))[idx];
            mn.x = fminf(mn.x, v.x); mn.y = fminf(mn.y, v.y);
            mn.z = fminf(mn.z, v.z); mn.w = fminf(mn.w, v.w);
        }
        float4 o;
        o.x = mn.x + bc; o.y = mn.y + bc; o.z = mn.z + bc; o.w = mn.w + bc;
        o4[(size_t)c * (B_ROWS / 4) + idx] = o;
    }
}

extern "C" void kernel_launch(void* const* d_in, const int* in_sizes, int n_in,
                              void* d_out, int out_size, void* d_ws, size_t ws_size,
                              hipStream_t stream) {
    const float* x    = (const float*)d_in[0];
    const float* w    = (const float*)d_in[1];
    const float* bl   = (const float*)d_in[2];
    const float* wg   = (const float*)d_in[3];
    const float* bg   = (const float*)d_in[4];
    const float* bias = (const float*)d_in[5];

    unsigned short* P = (unsigned short*)d_ws;                 // 256 KB packed bf16 W
    float* mparts     = (float*)((char*)d_ws + 262144);        // 8 x 256 KB partial mins
    float* out        = (float*)d_out;

    hipLaunchKernelGGL(pack_w, dim3(256), dim3(64), 0, stream, w, P);
    hipLaunchKernelGGL(gemm_gn_stream, dim3(4096), dim3(256), 0, stream,
                       x, P, bl, wg, bg, mparts);
    hipLaunchKernelGGL(bcast_out, dim3(2048), dim3(256), 0, stream, mparts, bias, out);
}